// Round 11
// baseline (1228.694 us; speedup 1.0000x reference)
//
#include <hip/hip_runtime.h>
#include <cstdint>

using u16 = unsigned short;
using u32 = unsigned int;

typedef __bf16 bf16x8 __attribute__((ext_vector_type(8)));
typedef float f32x4 __attribute__((ext_vector_type(4)));

__device__ __forceinline__ float bf2f(u16 u) {
    u32 v = ((u32)u) << 16; float f; __builtin_memcpy(&f, &v, 4); return f;
}
__device__ __forceinline__ u16 f2bf(float f) {
    u32 u; __builtin_memcpy(&u, &f, 4);
    u32 r = (u + 0x7fffu + ((u >> 16) & 1u)) >> 16; return (u16)r;
}
__device__ __forceinline__ u32 pack2(float a, float b) {
    return (u32)f2bf(a) | ((u32)f2bf(b) << 16);
}
// bijective chunked XCD swizzle (m204)
__device__ __forceinline__ int xcd_swz(int orig, int nwg) {
    int q = nwg >> 3, r8 = nwg & 7;
    int xcd = orig & 7, slot = orig >> 3;
    return (xcd < r8 ? xcd * (q + 1) : r8 * (q + 1) + (xcd - r8) * q) + slot;
}
// async global->LDS, 16B/lane; LDS dest wave-uniform base + lane*16
__device__ __forceinline__ void async_cp16(const u16* g, u16* l) {
    __builtin_amdgcn_global_load_lds(
        (const __attribute__((address_space(1))) void*)g,
        (__attribute__((address_space(3))) void*)l, 16, 0, 0);
}

// ---------------------------------------------------------------------------
// weight transpose: w [R][C] fp32 -> wt [C][R] bf16
// ---------------------------------------------------------------------------
__global__ __launch_bounds__(256) void transp_k(const float* __restrict__ in,
                                                u16* __restrict__ outp,
                                                int R, int C) {
    __shared__ alignas(16) u16 t[32][33];
    int tx = threadIdx.x & 31, ty = threadIdx.x >> 5;
    int bx = blockIdx.x * 32, by = blockIdx.y * 32;
#pragma unroll
    for (int i = 0; i < 4; ++i)
        t[ty + i * 8][tx] = f2bf(in[(size_t)(by + ty + i * 8) * C + bx + tx]);
    __syncthreads();
#pragma unroll
    for (int i = 0; i < 4; ++i)
        outp[(size_t)(bx + ty + i * 8) * R + by + tx] = t[tx][ty + i * 8];
}

// ---------------------------------------------------------------------------
// Fused LN1 + window mix (unchanged from round-10 pass)
// ---------------------------------------------------------------------------
__global__ __launch_bounds__(512, 2) void spatial_k(const float* __restrict__ xin,
                                                    const float* __restrict__ g1,
                                                    const float* __restrict__ b1,
                                                    const float* __restrict__ sw,
                                                    const float* __restrict__ sb,
                                                    float* __restrict__ outp) {
    __shared__ alignas(16) u16 raw[49 * 512];        // 50176 B (ln bf16)
    __shared__ float swl[16 * 4 * 49];               // 12544 B (sw chunk)
    __shared__ int toks[49];
    const int tid = threadIdx.x;
    const int wid = blockIdx.x;
    const int b = wid / 81, rem = wid % 81;
    const int wy = rem / 9, wx = rem % 9;

    if (tid < 49) {
        int py = tid / 7, px = tid % 7;
        int y = wy * 7 + py - 4, x = wx * 7 + px - 4;  // PT=PL=4
        toks[tid] = ((unsigned)y < 56u && (unsigned)x < 56u)
                        ? (b * 3136 + y * 56 + x) : -1;
    }
    __syncthreads();

    const int l = tid & 63, wvi = tid >> 6;
    float g1v[8], b1v[8];
#pragma unroll
    for (int j = 0; j < 8; ++j) { g1v[j] = g1[l * 8 + j]; b1v[j] = b1[l * 8 + j]; }
    for (int p = wvi; p < 49; p += 8) {
        int tk = toks[p];
        uint4 w = make_uint4(0, 0, 0, 0);
        if (tk >= 0) {
            const float4* pp = (const float4*)(xin + (size_t)tk * 512 + l * 8);
            float4 a = pp[0], bb = pp[1];
            float v[8] = {a.x, a.y, a.z, a.w, bb.x, bb.y, bb.z, bb.w};
            float s = 0.f, qq = 0.f;
#pragma unroll
            for (int j = 0; j < 8; ++j) { s += v[j]; qq += v[j] * v[j]; }
#pragma unroll
            for (int off = 1; off < 64; off <<= 1) {
                s += __shfl_xor(s, off); qq += __shfl_xor(qq, off);
            }
            float m = s * (1.f / 512.f);
            float var = qq * (1.f / 512.f) - m * m;
            float r = rsqrtf(var + 1e-5f);
            float o[8];
#pragma unroll
            for (int j = 0; j < 8; ++j)
                o[j] = (v[j] - m) * r * g1v[j] + b1v[j];
            w.x = pack2(o[0], o[1]); w.y = pack2(o[2], o[3]);
            w.z = pack2(o[4], o[5]); w.w = pack2(o[6], o[7]);
        }
        *(uint4*)(raw + p * 512 + l * 8) = w;
    }
    __syncthreads();

    const int c = tid;
    const int h = c >> 5;
    float lnv[49];
#pragma unroll
    for (int j = 0; j < 49; ++j) lnv[j] = bf2f(raw[j * 512 + c]);

    for (int pc0 = 0; pc0 < 49; pc0 += 4) {
        const int pc = (49 - pc0) < 4 ? (49 - pc0) : 4;
        for (int idx = tid; idx < 16 * pc * 49; idx += 512) {
            int hh = idx / (pc * 49), r2 = idx % (pc * 49);
            int p2 = r2 / 49, j2 = r2 % 49;
            swl[hh * 196 + p2 * 49 + j2] = sw[(size_t)hh * 2401 + (pc0 + p2) * 49 + j2];
        }
        __syncthreads();
        for (int p = 0; p < pc; ++p) {
            int tk = toks[pc0 + p];
            if (tk >= 0) {
                const float* swp = swl + h * 196 + p * 49;
                float acc = 0.f;
#pragma unroll
                for (int j = 0; j < 49; ++j)
                    acc += swp[j] * lnv[j];
                float o = acc + sb[h * 49 + pc0 + p] + xin[(size_t)tk * 512 + c];
                outp[(size_t)tk * 512 + c] = o;
            }
        }
        __syncthreads();
    }
}

// ---------------------------------------------------------------------------
// LN2 for a row-chunk (unchanged)
// ---------------------------------------------------------------------------
__global__ __launch_bounds__(512) void ln2_k(const float* __restrict__ xm,
                                             const float* __restrict__ g2,
                                             const float* __restrict__ b2,
                                             u16* __restrict__ outc, int row0) {
    const int lrow = blockIdx.x * 8 + (threadIdx.x >> 6);
    const int l = threadIdx.x & 63;
    const size_t gbase = (size_t)(row0 + lrow) * 512 + l * 8;
    const float4* p = (const float4*)(xm + gbase);
    float4 a = p[0], b = p[1];
    float v[8] = {a.x, a.y, a.z, a.w, b.x, b.y, b.z, b.w};
    float s = 0.f, qq = 0.f;
#pragma unroll
    for (int j = 0; j < 8; ++j) { s += v[j]; qq += v[j] * v[j]; }
#pragma unroll
    for (int off = 1; off < 64; off <<= 1) {
        s += __shfl_xor(s, off); qq += __shfl_xor(qq, off);
    }
    float m = s * (1.f / 512.f);
    float var = qq * (1.f / 512.f) - m * m;
    float r = rsqrtf(var + 1e-5f);
    float o[8];
#pragma unroll
    for (int j = 0; j < 8; ++j)
        o[j] = (v[j] - m) * r * g2[l * 8 + j] + b2[l * 8 + j];
    uint4 w;
    w.x = pack2(o[0], o[1]); w.y = pack2(o[2], o[3]);
    w.z = pack2(o[4], o[5]); w.w = pack2(o[6], o[7]);
    *(uint4*)(outc + (size_t)lrow * 512 + l * 8) = w;
}

// ---------------------------------------------------------------------------
// MFMA GEMM, 2-phase double-buffered (T3-minimum): 128x128 tile, BK=64,
// 4 waves (2x2), gload_lds width-16 staging (pre-swizzled source), 64 KB LDS
// (2 buffers), ONE vmcnt(0)+barrier per K-step AFTER MFMA so the next tile's
// loads fly under compute. XCD-swizzled 1D grid.
// EPI==0: bias + fast tanh-GELU -> Out bf16 (chunk-local rows)
// EPI==1: two-phase LDS C-tile + dense float4 residual RMW on f32 Out
// ---------------------------------------------------------------------------
template <int KD, int ND, int EPI>
__global__ __launch_bounds__(256) void gemm_k(const u16* __restrict__ A,
                                              const u16* __restrict__ Wt,
                                              const float* __restrict__ bias,
                                              void* __restrict__ Out, int row0) {
    __shared__ alignas(16) u16 smem[2 * 2 * 128 * 64];   // [buf][A|B], 64 KB
    const int tid = threadIdx.x;
    const int l = tid & 63, w = tid >> 6;
    const int wm = w >> 1, wn = w & 1;
    const int lr = l & 15, lk = l >> 4;

    const int wg = xcd_swz(blockIdx.x, gridDim.x);
    constexpr int NTN = ND / 128;
    const int bm = wg / NTN, bn = wg % NTN;   // consecutive wg share bm

    // staging addresses: physical slot s holds logical chunk pc^(rr&7)
    const u16* gA[4]; const u16* gB[4];
    int lofs[4];
#pragma unroll
    for (int i = 0; i < 4; ++i) {
        int s = (w * 4 + i) * 64 + l;
        int rr = s >> 3, pc = s & 7, cc = pc ^ (rr & 7);
        gA[i] = A  + (size_t)(bm * 128 + rr) * KD + cc * 8;
        gB[i] = Wt + (size_t)(bn * 128 + rr) * KD + cc * 8;
        lofs[i] = (w * 4 + i) * 512;   // wave-uniform LDS base (element offset)
    }

    f32x4 acc[4][4] = {};

    // prologue: stage tile 0 into buf 0
#pragma unroll
    for (int i = 0; i < 4; ++i) async_cp16(gA[i], smem + lofs[i]);
#pragma unroll
    for (int i = 0; i < 4; ++i) async_cp16(gB[i], smem + 8192 + lofs[i]);
#pragma unroll
    for (int i = 0; i < 4; ++i) { gA[i] += 64; gB[i] += 64; }
    asm volatile("s_waitcnt vmcnt(0)" ::: "memory");
    __syncthreads();

    int cur = 0;
    for (int ks = 0; ks < KD; ks += 64) {
        // issue next tile's loads into the other buffer (flies under MFMA)
        if (ks + 64 < KD) {
            u16* dst = smem + (cur ^ 1) * 16384;
#pragma unroll
            for (int i = 0; i < 4; ++i) async_cp16(gA[i], dst + lofs[i]);
#pragma unroll
            for (int i = 0; i < 4; ++i) async_cp16(gB[i], dst + 8192 + lofs[i]);
#pragma unroll
            for (int i = 0; i < 4; ++i) { gA[i] += 64; gB[i] += 64; }
        }
        const u16* As = smem + cur * 16384;
        const u16* Bs = As + 8192;
#pragma unroll
        for (int kk = 0; kk < 2; ++kk) {
            bf16x8 af[4], bfr[4];
#pragma unroll
            for (int f = 0; f < 4; ++f) {
                int ra = wm * 64 + f * 16 + lr;
                af[f] = *reinterpret_cast<const bf16x8*>(
                    As + ra * 64 + (((kk * 4 + lk) ^ (ra & 7)) * 8));
                int rb = wn * 64 + f * 16 + lr;
                bfr[f] = *reinterpret_cast<const bf16x8*>(
                    Bs + rb * 64 + (((kk * 4 + lk) ^ (rb & 7)) * 8));
            }
#pragma unroll
            for (int fi = 0; fi < 4; ++fi)
#pragma unroll
                for (int fj = 0; fj < 4; ++fj)
                    acc[fi][fj] = __builtin_amdgcn_mfma_f32_16x16x32_bf16(
                        af[fi], bfr[fj], acc[fi][fj], 0, 0, 0);
        }
        asm volatile("s_waitcnt vmcnt(0)" ::: "memory");
        __syncthreads();
        cur ^= 1;
    }

    if (EPI == 0) {
        // bias + fast tanh-GELU -> bf16 Out. D row=(lane>>4)*4+reg, col=lane&15
        u16* O16 = (u16*)Out;
#pragma unroll
        for (int fi = 0; fi < 4; ++fi) {
#pragma unroll
            for (int fj = 0; fj < 4; ++fj) {
#pragma unroll
                for (int rr = 0; rr < 4; ++rr) {
                    int mrow = bm * 128 + wm * 64 + fi * 16 + lk * 4 + rr;
                    int ncol = bn * 128 + wn * 64 + fj * 16 + lr;
                    float v = acc[fi][fj][rr] + bias[ncol];
                    // gelu(v) ~= v * sigmoid(2u), u = 0.79788456(v + 0.044715 v^3)
                    float u_ = v * (0.7978845608028654f + 0.03567740813636141f * v * v);
                    float ge = v / (1.f + __expf(-2.f * u_));
                    O16[(size_t)mrow * ND + ncol] = f2bf(ge);
                }
            }
        }
    } else {
        // two-phase 64x128 f32 LDS C-tile (32 KB) + dense float4 residual RMW
        float* Of = (float*)Out;
        float* Cs = (float*)smem;
#pragma unroll
        for (int half = 0; half < 2; ++half) {
            if (wm == half) {
#pragma unroll
                for (int fi = 0; fi < 4; ++fi) {
#pragma unroll
                    for (int fj = 0; fj < 4; ++fj) {
                        int col = wn * 64 + fj * 16 + lr;
                        float bcol = bias[bn * 128 + col];
#pragma unroll
                        for (int rr = 0; rr < 4; ++rr) {
                            int row = fi * 16 + lk * 4 + rr;
                            Cs[row * 128 + col] = acc[fi][fj][rr] + bcol;
                        }
                    }
                }
            }
            __syncthreads();
#pragma unroll
            for (int it = 0; it < 4; ++it) {
                int row = it * 16 + (tid >> 4);
                int cb = (tid & 15) * 8;
                float4 c0 = *(const float4*)(Cs + row * 128 + cb);
                float4 c1 = *(const float4*)(Cs + row * 128 + cb + 4);
                size_t go = (size_t)(row0 + bm * 128 + half * 64 + row) * ND
                            + bn * 128 + cb;
                float4 r0 = *(const float4*)(Of + go);
                float4 r1 = *(const float4*)(Of + go + 4);
                r0.x += c0.x; r0.y += c0.y; r0.z += c0.z; r0.w += c0.w;
                r1.x += c1.x; r1.y += c1.y; r1.z += c1.z; r1.w += c1.w;
                *(float4*)(Of + go) = r0;
                *(float4*)(Of + go + 4) = r1;
            }
            __syncthreads();
        }
    }
}

// ---------------------------------------------------------------------------
extern "C" void kernel_launch(void* const* d_in, const int* in_sizes, int n_in,
                              void* d_out, int out_size, void* d_ws, size_t ws_size,
                              hipStream_t stream) {
    const float* x   = (const float*)d_in[0];
    const float* g1  = (const float*)d_in[1];
    const float* b1  = (const float*)d_in[2];
    const float* sw  = (const float*)d_in[3];
    const float* sb  = (const float*)d_in[4];
    const float* g2  = (const float*)d_in[5];
    const float* b2  = (const float*)d_in[6];
    const float* w1  = (const float*)d_in[7];
    const float* bb1 = (const float*)d_in[8];
    const float* w2  = (const float*)d_in[9];
    const float* bb2 = (const float*)d_in[10];
    float* out = (float*)d_out;

    char* ws = (char*)d_ws;
    u16* w1t = (u16*)ws;                                  // [2048][512]  2 MB
    u16* w2t = (u16*)(ws + 2097152);                      // [512][2048]  2 MB
    size_t cbase = 2u * 2097152;                          // chunk area

    // per 128-row tile: ln2c 128*512*2 = 131072 B, hid 128*2048*2 = 524288 B
    long avail = (long)ws_size - (long)cbase;
    long maxT = avail / 655360;
    int chunkT = (int)(maxT < 1 ? 1 : (maxT > 784 ? 784 : maxT));
    u16* ln2c = (u16*)(ws + cbase);
    u16* hid  = (u16*)(ws + cbase + (size_t)chunkT * 131072);

    transp_k<<<dim3(64, 16), 256, 0, stream>>>(w1, w1t, 512, 2048);
    transp_k<<<dim3(16, 64), 256, 0, stream>>>(w2, w2t, 2048, 512);
    spatial_k<<<2592, 512, 0, stream>>>(x, g1, b1, sw, sb, out);
    for (int t0 = 0; t0 < 784; t0 += chunkT) {
        int nt = (784 - t0) < chunkT ? (784 - t0) : chunkT;
        ln2_k<<<nt * 16, 512, 0, stream>>>(out, g2, b2, ln2c, t0 * 128);
        gemm_k<512, 2048, 0><<<nt * 16, 256, 0, stream>>>(
            ln2c, w1t, bb1, hid, 0);
        gemm_k<2048, 512, 1><<<nt * 4, 256, 0, stream>>>(
            hid, w2t, bb2, out, t0 * 128);
    }
}

// Round 12
// 1033.228 us; speedup vs baseline: 1.1892x; 1.1892x over previous
//
#include <hip/hip_runtime.h>
#include <cstdint>

using u16 = unsigned short;
using u32 = unsigned int;

typedef __bf16 bf16x8 __attribute__((ext_vector_type(8)));
typedef float f32x4 __attribute__((ext_vector_type(4)));

__device__ __forceinline__ float bf2f(u16 u) {
    u32 v = ((u32)u) << 16; float f; __builtin_memcpy(&f, &v, 4); return f;
}
__device__ __forceinline__ u16 f2bf(float f) {
    u32 u; __builtin_memcpy(&u, &f, 4);
    u32 r = (u + 0x7fffu + ((u >> 16) & 1u)) >> 16; return (u16)r;
}
__device__ __forceinline__ u32 pack2(float a, float b) {
    return (u32)f2bf(a) | ((u32)f2bf(b) << 16);
}
// bijective chunked XCD swizzle (m204)
__device__ __forceinline__ int xcd_swz(int orig, int nwg) {
    int q = nwg >> 3, r8 = nwg & 7;
    int xcd = orig & 7, slot = orig >> 3;
    return (xcd < r8 ? xcd * (q + 1) : r8 * (q + 1) + (xcd - r8) * q) + slot;
}
// async global->LDS, 16B/lane; LDS dest wave-uniform base + lane*16
__device__ __forceinline__ void async_cp16(const u16* g, u16* l) {
    __builtin_amdgcn_global_load_lds(
        (const __attribute__((address_space(1))) void*)g,
        (__attribute__((address_space(3))) void*)l, 16, 0, 0);
}

// ---------------------------------------------------------------------------
// weight transpose: w [R][C] fp32 -> wt [C][R] bf16
// ---------------------------------------------------------------------------
__global__ __launch_bounds__(256) void transp_k(const float* __restrict__ in,
                                                u16* __restrict__ outp,
                                                int R, int C) {
    __shared__ alignas(16) u16 t[32][33];
    int tx = threadIdx.x & 31, ty = threadIdx.x >> 5;
    int bx = blockIdx.x * 32, by = blockIdx.y * 32;
#pragma unroll
    for (int i = 0; i < 4; ++i)
        t[ty + i * 8][tx] = f2bf(in[(size_t)(by + ty + i * 8) * C + bx + tx]);
    __syncthreads();
#pragma unroll
    for (int i = 0; i < 4; ++i)
        outp[(size_t)(bx + ty + i * 8) * R + by + tx] = t[tx][ty + i * 8];
}

// ---------------------------------------------------------------------------
// Fused LN1 + window mix (unchanged from round-10 pass)
// ---------------------------------------------------------------------------
__global__ __launch_bounds__(512, 2) void spatial_k(const float* __restrict__ xin,
                                                    const float* __restrict__ g1,
                                                    const float* __restrict__ b1,
                                                    const float* __restrict__ sw,
                                                    const float* __restrict__ sb,
                                                    float* __restrict__ outp) {
    __shared__ alignas(16) u16 raw[49 * 512];        // 50176 B (ln bf16)
    __shared__ float swl[16 * 4 * 49];               // 12544 B (sw chunk)
    __shared__ int toks[49];
    const int tid = threadIdx.x;
    const int wid = blockIdx.x;
    const int b = wid / 81, rem = wid % 81;
    const int wy = rem / 9, wx = rem % 9;

    if (tid < 49) {
        int py = tid / 7, px = tid % 7;
        int y = wy * 7 + py - 4, x = wx * 7 + px - 4;  // PT=PL=4
        toks[tid] = ((unsigned)y < 56u && (unsigned)x < 56u)
                        ? (b * 3136 + y * 56 + x) : -1;
    }
    __syncthreads();

    const int l = tid & 63, wvi = tid >> 6;
    float g1v[8], b1v[8];
#pragma unroll
    for (int j = 0; j < 8; ++j) { g1v[j] = g1[l * 8 + j]; b1v[j] = b1[l * 8 + j]; }
    for (int p = wvi; p < 49; p += 8) {
        int tk = toks[p];
        uint4 w = make_uint4(0, 0, 0, 0);
        if (tk >= 0) {
            const float4* pp = (const float4*)(xin + (size_t)tk * 512 + l * 8);
            float4 a = pp[0], bb = pp[1];
            float v[8] = {a.x, a.y, a.z, a.w, bb.x, bb.y, bb.z, bb.w};
            float s = 0.f, qq = 0.f;
#pragma unroll
            for (int j = 0; j < 8; ++j) { s += v[j]; qq += v[j] * v[j]; }
#pragma unroll
            for (int off = 1; off < 64; off <<= 1) {
                s += __shfl_xor(s, off); qq += __shfl_xor(qq, off);
            }
            float m = s * (1.f / 512.f);
            float var = qq * (1.f / 512.f) - m * m;
            float r = rsqrtf(var + 1e-5f);
            float o[8];
#pragma unroll
            for (int j = 0; j < 8; ++j)
                o[j] = (v[j] - m) * r * g1v[j] + b1v[j];
            w.x = pack2(o[0], o[1]); w.y = pack2(o[2], o[3]);
            w.z = pack2(o[4], o[5]); w.w = pack2(o[6], o[7]);
        }
        *(uint4*)(raw + p * 512 + l * 8) = w;
    }
    __syncthreads();

    const int c = tid;
    const int h = c >> 5;
    float lnv[49];
#pragma unroll
    for (int j = 0; j < 49; ++j) lnv[j] = bf2f(raw[j * 512 + c]);

    for (int pc0 = 0; pc0 < 49; pc0 += 4) {
        const int pc = (49 - pc0) < 4 ? (49 - pc0) : 4;
        for (int idx = tid; idx < 16 * pc * 49; idx += 512) {
            int hh = idx / (pc * 49), r2 = idx % (pc * 49);
            int p2 = r2 / 49, j2 = r2 % 49;
            swl[hh * 196 + p2 * 49 + j2] = sw[(size_t)hh * 2401 + (pc0 + p2) * 49 + j2];
        }
        __syncthreads();
        for (int p = 0; p < pc; ++p) {
            int tk = toks[pc0 + p];
            if (tk >= 0) {
                const float* swp = swl + h * 196 + p * 49;
                float acc = 0.f;
#pragma unroll
                for (int j = 0; j < 49; ++j)
                    acc += swp[j] * lnv[j];
                float o = acc + sb[h * 49 + pc0 + p] + xin[(size_t)tk * 512 + c];
                outp[(size_t)tk * 512 + c] = o;
            }
        }
        __syncthreads();
    }
}

// ---------------------------------------------------------------------------
// LN2 for a row-chunk (unchanged)
// ---------------------------------------------------------------------------
__global__ __launch_bounds__(512) void ln2_k(const float* __restrict__ xm,
                                             const float* __restrict__ g2,
                                             const float* __restrict__ b2,
                                             u16* __restrict__ outc, int row0) {
    const int lrow = blockIdx.x * 8 + (threadIdx.x >> 6);
    const int l = threadIdx.x & 63;
    const size_t gbase = (size_t)(row0 + lrow) * 512 + l * 8;
    const float4* p = (const float4*)(xm + gbase);
    float4 a = p[0], b = p[1];
    float v[8] = {a.x, a.y, a.z, a.w, b.x, b.y, b.z, b.w};
    float s = 0.f, qq = 0.f;
#pragma unroll
    for (int j = 0; j < 8; ++j) { s += v[j]; qq += v[j] * v[j]; }
#pragma unroll
    for (int off = 1; off < 64; off <<= 1) {
        s += __shfl_xor(s, off); qq += __shfl_xor(qq, off);
    }
    float m = s * (1.f / 512.f);
    float var = qq * (1.f / 512.f) - m * m;
    float r = rsqrtf(var + 1e-5f);
    float o[8];
#pragma unroll
    for (int j = 0; j < 8; ++j)
        o[j] = (v[j] - m) * r * g2[l * 8 + j] + b2[l * 8 + j];
    uint4 w;
    w.x = pack2(o[0], o[1]); w.y = pack2(o[2], o[3]);
    w.z = pack2(o[4], o[5]); w.w = pack2(o[6], o[7]);
    *(uint4*)(outc + (size_t)lrow * 512 + l * 8) = w;
}

// ---------------------------------------------------------------------------
// MFMA GEMM, 256x256 tile, 8 waves (2m x 4n), BK=64, 2-phase double-buffered
// gload_lds staging (pre-swizzled source chunk c^(r&7), linear LDS dest),
// 128 KB LDS, one vmcnt(0)+barrier per K-step AFTER the 512-MFMA block.
// Per-wave output 128x64 (acc[8][4]). XCD-swizzled 1D grid.
// EPI==0: bias + fast tanh-GELU -> Out bf16 (chunk-local rows)
// EPI==1: two-phase (by wm) 128x256 f32 LDS C-tile + dense float4 RMW
// ---------------------------------------------------------------------------
template <int KD, int ND, int EPI>
__global__ __launch_bounds__(512) void gemm_k(const u16* __restrict__ A,
                                              const u16* __restrict__ Wt,
                                              const float* __restrict__ bias,
                                              void* __restrict__ Out, int row0) {
    __shared__ alignas(16) u16 smem[2 * 32768];   // [buf][A(16K u16)|B(16K u16)]
    const int tid = threadIdx.x;
    const int l = tid & 63, wid = tid >> 6;
    const int wm = wid >> 2, wn = wid & 3;
    const int lr = l & 15, lk = l >> 4;

    const int wg = xcd_swz(blockIdx.x, gridDim.x);
    constexpr int NTN = ND / 256;
    const int bm = wg / NTN, bn = wg % NTN;   // consecutive wg share bm

    // staging: physical slot s holds logical chunk pc^(rr&7); 4 A + 4 B per thread
    const u16* gA[4]; const u16* gB[4];
    int lofs[4];
#pragma unroll
    for (int i = 0; i < 4; ++i) {
        int s = (wid * 4 + i) * 64 + l;            // [0, 2048)
        int rr = s >> 3, pc = s & 7, cc = pc ^ (rr & 7);
        gA[i] = A  + (size_t)(bm * 256 + rr) * KD + cc * 8;
        gB[i] = Wt + (size_t)(bn * 256 + rr) * KD + cc * 8;
        lofs[i] = (wid * 4 + i) * 512;             // element offset, wave-uniform
    }

    f32x4 acc[8][4] = {};

    // prologue: stage tile 0 into buf 0
#pragma unroll
    for (int i = 0; i < 4; ++i) async_cp16(gA[i], smem + lofs[i]);
#pragma unroll
    for (int i = 0; i < 4; ++i) async_cp16(gB[i], smem + 16384 + lofs[i]);
#pragma unroll
    for (int i = 0; i < 4; ++i) { gA[i] += 64; gB[i] += 64; }
    asm volatile("s_waitcnt vmcnt(0)" ::: "memory");
    __syncthreads();

    int cur = 0;
    for (int ks = 0; ks < KD; ks += 64) {
        // issue next tile's loads into the other buffer (fly under MFMA)
        if (ks + 64 < KD) {
            u16* dst = smem + (cur ^ 1) * 32768;
#pragma unroll
            for (int i = 0; i < 4; ++i) async_cp16(gA[i], dst + lofs[i]);
#pragma unroll
            for (int i = 0; i < 4; ++i) async_cp16(gB[i], dst + 16384 + lofs[i]);
#pragma unroll
            for (int i = 0; i < 4; ++i) { gA[i] += 64; gB[i] += 64; }
        }
        const u16* As = smem + cur * 32768;
        const u16* Bs = As + 16384;
#pragma unroll
        for (int kk = 0; kk < 2; ++kk) {
            bf16x8 af[8], bfr[4];
#pragma unroll
            for (int f = 0; f < 8; ++f) {
                int ra = wm * 128 + f * 16 + lr;
                af[f] = *reinterpret_cast<const bf16x8*>(
                    As + ra * 64 + (((kk * 4 + lk) ^ (ra & 7)) * 8));
            }
#pragma unroll
            for (int f = 0; f < 4; ++f) {
                int rb = wn * 64 + f * 16 + lr;
                bfr[f] = *reinterpret_cast<const bf16x8*>(
                    Bs + rb * 64 + (((kk * 4 + lk) ^ (rb & 7)) * 8));
            }
#pragma unroll
            for (int fi = 0; fi < 8; ++fi)
#pragma unroll
                for (int fj = 0; fj < 4; ++fj)
                    acc[fi][fj] = __builtin_amdgcn_mfma_f32_16x16x32_bf16(
                        af[fi], bfr[fj], acc[fi][fj], 0, 0, 0);
        }
        asm volatile("s_waitcnt vmcnt(0)" ::: "memory");
        __syncthreads();
        cur ^= 1;
    }

    if (EPI == 0) {
        // bias + fast tanh-GELU -> bf16 Out. D row=(lane>>4)*4+reg, col=lane&15
        u16* O16 = (u16*)Out;
#pragma unroll
        for (int fi = 0; fi < 8; ++fi) {
#pragma unroll
            for (int fj = 0; fj < 4; ++fj) {
#pragma unroll
                for (int rr = 0; rr < 4; ++rr) {
                    int mrow = bm * 256 + wm * 128 + fi * 16 + lk * 4 + rr;
                    int ncol = bn * 256 + wn * 64 + fj * 16 + lr;
                    float v = acc[fi][fj][rr] + bias[ncol];
                    float u_ = v * (0.7978845608028654f + 0.03567740813636141f * v * v);
                    float ge = v / (1.f + __expf(-2.f * u_));
                    O16[(size_t)mrow * ND + ncol] = f2bf(ge);
                }
            }
        }
    } else {
        // two-phase (by wm): 128x256 f32 LDS C-tile (128 KB, exact smem reuse)
        float* Of = (float*)Out;
        float* Cs = (float*)smem;
#pragma unroll
        for (int half = 0; half < 2; ++half) {
            if (wm == half) {
#pragma unroll
                for (int fi = 0; fi < 8; ++fi) {
#pragma unroll
                    for (int fj = 0; fj < 4; ++fj) {
                        int col = wn * 64 + fj * 16 + lr;
                        float bcol = bias[bn * 256 + col];
#pragma unroll
                        for (int rr = 0; rr < 4; ++rr) {
                            int row = fi * 16 + lk * 4 + rr;   // 0..127
                            Cs[row * 256 + col] = acc[fi][fj][rr] + bcol;
                        }
                    }
                }
            }
            __syncthreads();
#pragma unroll
            for (int it = 0; it < 8; ++it) {
                int row = it * 16 + (tid >> 5);
                int cf = (tid & 31) * 8;
                float4 c0 = *(const float4*)(Cs + row * 256 + cf);
                float4 c1 = *(const float4*)(Cs + row * 256 + cf + 4);
                size_t go = (size_t)(row0 + bm * 256 + half * 128 + row) * ND
                            + bn * 256 + cf;
                float4 r0 = *(const float4*)(Of + go);
                float4 r1 = *(const float4*)(Of + go + 4);
                r0.x += c0.x; r0.y += c0.y; r0.z += c0.z; r0.w += c0.w;
                r1.x += c1.x; r1.y += c1.y; r1.z += c1.z; r1.w += c1.w;
                *(float4*)(Of + go) = r0;
                *(float4*)(Of + go + 4) = r1;
            }
            __syncthreads();
        }
    }
}

// ---------------------------------------------------------------------------
extern "C" void kernel_launch(void* const* d_in, const int* in_sizes, int n_in,
                              void* d_out, int out_size, void* d_ws, size_t ws_size,
                              hipStream_t stream) {
    const float* x   = (const float*)d_in[0];
    const float* g1  = (const float*)d_in[1];
    const float* b1  = (const float*)d_in[2];
    const float* sw  = (const float*)d_in[3];
    const float* sb  = (const float*)d_in[4];
    const float* g2  = (const float*)d_in[5];
    const float* b2  = (const float*)d_in[6];
    const float* w1  = (const float*)d_in[7];
    const float* bb1 = (const float*)d_in[8];
    const float* w2  = (const float*)d_in[9];
    const float* bb2 = (const float*)d_in[10];
    float* out = (float*)d_out;

    char* ws = (char*)d_ws;
    u16* w1t = (u16*)ws;                                  // [2048][512]  2 MB
    u16* w2t = (u16*)(ws + 2097152);                      // [512][2048]  2 MB
    size_t cbase = 2u * 2097152;                          // chunk area

    // per 128-row unit: ln2c 131072 B, hid 524288 B
    long avail = (long)ws_size - (long)cbase;
    long maxT = avail / 655360;
    int chunkT = (int)(maxT < 2 ? 2 : (maxT > 784 ? 784 : maxT));
    chunkT &= ~1;                                          // 256-row tiles
    u16* ln2c = (u16*)(ws + cbase);
    u16* hid  = (u16*)(ws + cbase + (size_t)chunkT * 131072);

    transp_k<<<dim3(64, 16), 256, 0, stream>>>(w1, w1t, 512, 2048);
    transp_k<<<dim3(16, 64), 256, 0, stream>>>(w2, w2t, 2048, 512);
    spatial_k<<<2592, 512, 0, stream>>>(x, g1, b1, sw, sb, out);
    for (int t0 = 0; t0 < 784; t0 += chunkT) {
        int nt = (784 - t0) < chunkT ? (784 - t0) : chunkT;
        int nt2 = nt >> 1;                                 // 256-row tiles
        ln2_k<<<nt * 16, 512, 0, stream>>>(out, g2, b2, ln2c, t0 * 128);
        gemm_k<512, 2048, 0><<<nt2 * 8, 512, 0, stream>>>(
            ln2c, w1t, bb1, hid, 0);
        gemm_k<2048, 512, 1><<<nt2 * 2, 512, 0, stream>>>(
            hid, w2t, bb2, out, t0 * 128);
    }
}